// Round 12
// baseline (125.051 us; speedup 1.0000x reference)
//
#include <hip/hip_runtime.h>
#include <stdint.h>

// ScaledDotProductAttention: B=16, Nq=Nk=4096, d=128, fp32 in/out, causal.
// Flash forward, bf16 MFMA 16x16x32, swapped-QK^T (lane-local softmax).
// Round-11 = Round-10 with the merge_kernel store type fixed (*(fx4*)op).
// KVBLK=32 + double-buffer (16KB x2 = 32KB LDS) -> staging hidden under
// compute AND 3 blocks/CU. Work split into EXACTLY-equal 44-unit blocks
// (768 blocks): per batch, group v = [tile 31-v ++ tile v] = 132 units cut at
// 44/88. <=2 pieces/block, <=3 partials/tile, 3-way merge (slot0 raw f32 in O,
// slots 1/2 bf16 in Pa). Tiles t<=10 single-piece -> direct write.
// ws: Kfrag 16MB | Vfrag 16MB | Pa 16MB @32M | Ml 2MB @48M  (NEED 50MB).

#define NB 16
#define NS 4096
#define DH 128
#define FRAG_U16 8192  // u16 elems per (batch, kv-block-of-64) fragment tile (16KB)

typedef float          fx4   __attribute__((ext_vector_type(4)));
typedef uint32_t       ux4   __attribute__((ext_vector_type(4)));
typedef __bf16         bfv8  __attribute__((ext_vector_type(8)));
typedef __bf16         bfv4  __attribute__((ext_vector_type(4)));
typedef unsigned short u16x4 __attribute__((ext_vector_type(4)));

typedef const uint32_t __attribute__((address_space(1))) glob_u32;
typedef uint32_t       __attribute__((address_space(3))) lds_u32;

__device__ __forceinline__ fx4 mfma16(bfv8 a, bfv8 b, fx4 c) {
  return __builtin_amdgcn_mfma_f32_16x16x32_bf16(a, b, c, 0, 0, 0);
}

// ---------------- fused prepass: K,V fp32 -> fragment-packed bf16 ----------------
// (unchanged; verified r4-r9) Fragment layouts (lane = g*16+ln16):
//  Kfrag[b][kvblk][tt(4)][c(4)][lane(64)][8]: K[b][kvb+16tt+ln16][32c+8g+e]
//  Vfrag[b][kvblk][dt(8)][c(2)][lane(64)][8]: V^T row d=16dt+ln16,
//      kv elems: e<4 -> kvb+32c+4g+e ; e>=4 -> kvb+32c+16+4g+(e-4)
__global__ void __launch_bounds__(256) prepack_kernel(
    const float* __restrict__ K, const float* __restrict__ V,
    unsigned short* __restrict__ Kf, unsigned short* __restrict__ Vf) {
  __shared__ __align__(16) unsigned short tile[64][136];
  const int bid = blockIdx.x;
  const int b = bid >> 6, kvblk = bid & 63;
  const int kvb = kvblk << 6;
  const int tid = threadIdx.x;
  const size_t fbase = ((size_t)(b * 64 + kvblk)) * FRAG_U16;

  {
    const int tt = tid >> 6, lane = tid & 63;
    const int ln16 = lane & 15, g = lane >> 4;
    const float* kp = K + (((size_t)(b * NS + kvb + 16 * tt + ln16)) << 7) + 8 * g;
    unsigned short* op = Kf + fbase + tt * 2048 + lane * 8;
#pragma unroll
    for (int c = 0; c < 4; ++c) {
      fx4 a0 = *(const fx4*)(kp + 32 * c);
      fx4 a1 = *(const fx4*)(kp + 32 * c + 4);
      bfv8 t;
#pragma unroll
      for (int j = 0; j < 4; ++j) {
        t[j]     = (__bf16)a0[j];
        t[j + 4] = (__bf16)a1[j];
      }
      *(ux4*)(op + c * 512) = __builtin_bit_cast(ux4, t);
    }
  }

  {
    const int r = tid >> 2, cq = tid & 3;
    const float* vp = V + (((size_t)(b * NS + kvb + r)) << 7) + 32 * cq;
#pragma unroll
    for (int h = 0; h < 4; ++h) {
      fx4 f0 = *(const fx4*)(vp + 8 * h);
      fx4 f1 = *(const fx4*)(vp + 8 * h + 4);
      bfv8 t;
#pragma unroll
      for (int j = 0; j < 4; ++j) {
        t[j]     = (__bf16)f0[j];
        t[j + 4] = (__bf16)f1[j];
      }
      *(ux4*)&tile[r][32 * cq + 8 * h] = __builtin_bit_cast(ux4, t);
    }
  }
  __syncthreads();
  {
    const int dt = tid >> 5, c = (tid >> 4) & 1, ln16 = tid & 15;
    const int d = 16 * dt + ln16;
    unsigned short* op = Vf + fbase + dt * 1024 + c * 512 + ln16 * 8;
#pragma unroll
    for (int g = 0; g < 4; ++g) {
      unsigned short e[8];
#pragma unroll
      for (int j = 0; j < 4; ++j) {
        e[j]     = tile[32 * c + 4 * g + j][d];
        e[j + 4] = tile[32 * c + 16 + 4 * g + j][d];
      }
      *(ux4*)(op + g * 128) = *(const ux4*)e;
    }
  }
}

// ---------------- main: causal flash attention, KVBLK=32, dbuf, 3 blocks/CU ----------------
// Units = 32-kv blocks. Tile t needs 4t+4 units. Group v: stream
// [tile 31-v: 128-4v units ++ tile v: 4v+4 units] cut at 44/88 -> 3 blocks
// of exactly 44 units. Piece modes: t<=10 -> 0 (direct O). else slot0 ->
// 1 (raw f32 -> O), slot1/2 -> 2 (bf16 -> Pa[pidx]). Ml[b][t][slot][2][128].
__global__ void __launch_bounds__(256, 3) attn_kernel(
    const float* __restrict__ Q, const unsigned short* __restrict__ Kf,
    const unsigned short* __restrict__ Vf, float* __restrict__ O,
    unsigned short* __restrict__ Pa, float* __restrict__ Ml, int split) {
  __shared__ __align__(16) unsigned char sm[32768];  // 2 x (K 8K | V 8K)

  const int wid  = blockIdx.x;
  const int tid  = threadIdx.x;
  const int w    = tid >> 6;
  const int lane = tid & 63;
  const int g    = lane >> 4;
  const int ln16 = lane & 15;

  int b;
  int t, u0, un, mode, pidx, slot;                 // active piece
  int t1 = 0, u1a = 0, u1b = 0, m1v = 0;           // second piece (if any)
  int again = 0;

  if (split) {
    const int n = wid >> 4;            // 0..47
    b = wid & 15;                      // wid%8 = b%8 -> XCD pin
    const int v = n / 3;
    const int k = n - 3 * v;
    const int L = 128 - 4 * v;         // big-tile units
    const int st = 44 * k, en = st + 44;
    if (st < L) {                      // piece A in big tile T=31-v, slot k
      t = 31 - v; u0 = st; un = (en < L) ? en : L;
      mode = (k == 0) ? 1 : 2;
      slot = k;
      pidx = (t <= 21) ? (t - 11) : (11 + 2 * (t - 22) + (k - 1));
      if (en > L) {                    // piece B: start of small tile v, slot 0
        t1 = v; u1a = 0; u1b = en - L;
        m1v = (v <= 10) ? 0 : 1;
        again = 1;
      }
    } else {                           // only small tile v, starting past 0 or at 0
      t = v; u0 = st - L; un = en - L;
      const int s = (u0 > 0) ? 1 : 0;
      mode = (v <= 10) ? 0 : ((s == 0) ? 1 : 2);
      slot = s;
      pidx = v - 11;                   // only used when mode==2 (v>=11, s==1)
    }
  } else {  // fallback: r5 static pairing, full tiles, direct write (grid 512)
    const int half = wid >> 8, ii = wid & 255;
    b = ii & 15;
    const int qi = ii >> 4;
    t = half ? qi : 31 - qi;
    u0 = 0; un = 4 * t + 4; mode = 0; pidx = 0; slot = 0;
  }

  const float SCALE = 0.12753102f;  // log2(e)/sqrt(128): exp2-domain scores
  const fx4 z4 = {0.f, 0.f, 0.f, 0.f};

  const unsigned char* kfB = (const unsigned char*)Kf + (size_t)b * 1048576;
  const unsigned char* vfB = (const unsigned char*)Vf + (size_t)b * 1048576;

  // stage 32-kv unit jb into LDS buffer at byte offset bo (16KB: K 8K | V 8K).
  // K half is contiguous (unit jb = bytes [jb*8K, jb*8K+8K) of Kf). V half is
  // 8 x 1KB chunks (c-dim of the 64-frag = kv half). Wave w moves 4 x 1KB.
#define STAGE(jb, bo)                                                          \
  do {                                                                         \
    const unsigned char* gk = kfB + (size_t)(jb) * 8192;                       \
    const unsigned char* gv = vfB + (size_t)((jb) >> 1) * 16384 + ((jb) & 1) * 1024; \
    _Pragma("unroll")                                                          \
    for (int ii = 0; ii < 2; ++ii) {                                           \
      __builtin_amdgcn_global_load_lds(                                        \
          (glob_u32*)(gk + w * 2048 + ii * 1024 + lane * 16),                  \
          (lds_u32*)(sm + (bo) + w * 2048 + ii * 1024), 16, 0, 0);             \
      const int dt_ = 2 * w + ii;                                              \
      __builtin_amdgcn_global_load_lds(                                        \
          (glob_u32*)(gv + dt_ * 2048 + lane * 16),                            \
          (lds_u32*)(sm + (bo) + 8192 + dt_ * 1024), 16, 0, 0);                \
    }                                                                          \
  } while (0)

  for (;;) {  // 1 or 2 pieces
    const int qw = (t << 7) + 32 * w;

    // Q fragments, pre-scaled (32 VGPR)
    bfv8 qf[2][4];
#pragma unroll
    for (int qt = 0; qt < 2; ++qt) {
#pragma unroll
      for (int c = 0; c < 4; ++c) {
        const float* qp = Q + (((size_t)(b * NS + qw + qt * 16 + ln16)) << 7) + 32 * c + 8 * g;
        fx4 a0 = *(const fx4*)qp;
        fx4 a1 = *(const fx4*)(qp + 4);
        bfv8 tt_;
#pragma unroll
        for (int j = 0; j < 4; ++j) {
          tt_[j]     = (__bf16)(a0[j] * SCALE);
          tt_[j + 4] = (__bf16)(a1[j] * SCALE);
        }
        qf[qt][c] = tt_;
      }
    }

    fx4 acc[2][8];
#pragma unroll
    for (int qt = 0; qt < 2; ++qt)
#pragma unroll
      for (int dt = 0; dt < 8; ++dt) acc[qt][dt] = z4;
    float mrun[2] = {-1e30f, -1e30f};
    float lsum[2] = {0.f, 0.f};

    const int nkvw = (qw >> 5) + 1;  // causal limit in 32-units

    STAGE(u0, 0);
    asm volatile("s_waitcnt vmcnt(0)" ::: "memory");
    __builtin_amdgcn_s_barrier();
    asm volatile("" ::: "memory");

    int cur = 0;
    for (int jb = u0; jb < un; ++jb) {
      if (jb + 1 < un) STAGE(jb + 1, (cur ^ 1) * 16384);  // hidden under compute

      if (jb < nkvw) {
        const unsigned char* kb = sm + cur * 16384;
        const unsigned char* vb = kb + 8192;

        // ---- QK^T (swapped: A=K rows->kv, B=Q cols->q) ----
        fx4 s[2][2];
        s[0][0] = z4; s[0][1] = z4; s[1][0] = z4; s[1][1] = z4;
        __builtin_amdgcn_s_setprio(1);
#pragma unroll
        for (int tt = 0; tt < 2; ++tt) {
#pragma unroll
          for (int c = 0; c < 4; ++c) {
            bfv8 kfr = *(const bfv8*)(kb + tt * 4096 + c * 1024 + lane * 16);
            s[0][tt] = mfma16(kfr, qf[0][c], s[0][tt]);
            s[1][tt] = mfma16(kfr, qf[1][c], s[1][tt]);
          }
        }
        __builtin_amdgcn_s_setprio(0);

        // ---- causal mask (near-diagonal units only) ----
        const int kvb = jb << 5;
        if (kvb + 31 > qw) {
#pragma unroll
          for (int qt = 0; qt < 2; ++qt) {
            const int qrow = qw + qt * 16 + ln16;
#pragma unroll
            for (int tt = 0; tt < 2; ++tt)
#pragma unroll
              for (int r = 0; r < 4; ++r) {
                int kvpos = kvb + 16 * tt + 4 * g + r;
                if (kvpos > qrow) s[qt][tt][r] = -1e30f;
              }
          }
        }

        // ---- online softmax (exp2 domain, lane-local, defer-max THR=8) ----
        bfv8 pb[2];
#pragma unroll
        for (int qt = 0; qt < 2; ++qt) {
          fx4 m4 = __builtin_elementwise_max(s[qt][0], s[qt][1]);
          float pm = fmaxf(fmaxf(m4[0], m4[1]), fmaxf(m4[2], m4[3]));
          pm = fmaxf(pm, __shfl_xor(pm, 16));
          pm = fmaxf(pm, __shfl_xor(pm, 32));
          float mq = mrun[qt];
          if (__any(pm > mq + 8.0f)) {
            float mn = fmaxf(mq, pm);
            float f  = __builtin_amdgcn_exp2f(mq - mn);
            lsum[qt] *= f;
#pragma unroll
            for (int dt = 0; dt < 8; ++dt) acc[qt][dt] *= f;
            mrun[qt] = mn;
            mq = mn;
          }
#pragma unroll
          for (int tt = 0; tt < 2; ++tt)
#pragma unroll
            for (int r = 0; r < 4; ++r)
              s[qt][tt][r] = __builtin_amdgcn_exp2f(s[qt][tt][r] - mq);
          fx4 r4 = s[qt][0] + s[qt][1];
          float rs = (r4[0] + r4[1]) + (r4[2] + r4[3]);
          rs += __shfl_xor(rs, 16);
          rs += __shfl_xor(rs, 32);
          lsum[qt] += rs;
          // pack P^T: j<4 -> kv 4g+j (tt=0), j>=4 -> 16+4g+(j-4) (tt=1)
          bfv8 tt_;
#pragma unroll
          for (int j = 0; j < 4; ++j) {
            tt_[j]     = (__bf16)s[qt][0][j];
            tt_[j + 4] = (__bf16)s[qt][1][j];
          }
          pb[qt] = tt_;
        }

        // ---- PV (A = V^T rows->d, B = P^T cols->q); V read inline ----
        __builtin_amdgcn_s_setprio(1);
#pragma unroll
        for (int dt = 0; dt < 8; ++dt) {
          bfv8 vfr = *(const bfv8*)(vb + dt * 1024 + lane * 16);
          acc[0][dt] = mfma16(vfr, pb[0], acc[0][dt]);
          acc[1][dt] = mfma16(vfr, pb[1], acc[1][dt]);
        }
        __builtin_amdgcn_s_setprio(0);
      }

      asm volatile("s_waitcnt vmcnt(0)" ::: "memory");  // drain next-tile stage
      __builtin_amdgcn_s_barrier();
      asm volatile("" ::: "memory");
      cur ^= 1;
    }

    // ---- epilogue per mode ----
    if (mode == 0) {  // final: O = acc/l
#pragma unroll
      for (int qt = 0; qt < 2; ++qt) {
        float inv = 1.0f / lsum[qt];
        float* ob = O + (((size_t)(b * NS + qw + qt * 16 + ln16)) << 7) + 4 * g;
#pragma unroll
        for (int dt = 0; dt < 8; ++dt) *(fx4*)(ob + 16 * dt) = acc[qt][dt] * inv;
      }
    } else {
      if (mode == 1) {  // slot0: raw f32 acc -> O (merged later)
#pragma unroll
        for (int qt = 0; qt < 2; ++qt) {
          float* ob = O + (((size_t)(b * NS + qw + qt * 16 + ln16)) << 7) + 4 * g;
#pragma unroll
          for (int dt = 0; dt < 8; ++dt) *(fx4*)(ob + 16 * dt) = acc[qt][dt];
        }
      } else {  // slot1/2: bf16 acc -> Pa[pidx]
#pragma unroll
        for (int qt = 0; qt < 2; ++qt) {
          const int row = 32 * w + 16 * qt + ln16;
          unsigned short* pp =
              Pa + (((size_t)((b * 32 + pidx) * 128 + row)) << 7) + 4 * g;
#pragma unroll
          for (int dt = 0; dt < 8; ++dt) {
            bfv4 t4;
#pragma unroll
            for (int j = 0; j < 4; ++j) t4[j] = (__bf16)acc[qt][dt][j];
            *(u16x4*)(pp + 16 * dt) = __builtin_bit_cast(u16x4, t4);
          }
        }
      }
      if (g == 0) {  // (m,l) -> Ml[b][t][slot][2][128]
        float* mlp = Ml + (size_t)((b * 32 + t) * 4 + slot) * 256;
#pragma unroll
        for (int qt = 0; qt < 2; ++qt) {
          const int row = 32 * w + 16 * qt + ln16;
          mlp[row]       = mrun[qt];
          mlp[128 + row] = lsum[qt];
        }
      }
    }

    if (!again) break;
    again = 0;
    t = t1; u0 = u1a; un = u1b; mode = m1v; pidx = 0; slot = 0;
  }
#undef STAGE
}

// ---------------- merge: 2 or 3 partials per tile (t=11..31) ----------------
__global__ void __launch_bounds__(256) merge_kernel(
    float* __restrict__ O, const unsigned short* __restrict__ Pa,
    const float* __restrict__ Ml) {
  const int gid = blockIdx.x * 256 + threadIdx.x;  // 1,376,256 threads exact
  const int d4  = gid & 31;
  const int rg  = gid >> 5;        // 0..43007
  const int b   = rg / 2688;       // 21 tiles * 128 rows
  const int r2  = rg - b * 2688;
  const int ti  = r2 >> 7;         // 0..20 -> t = 11+ti
  const int row = r2 & 127;
  const int t   = 11 + ti;

  const float* mlb = Ml + (size_t)((b * 32 + t) * 4) * 256;
  const float m0 = mlb[row],       l0 = mlb[128 + row];
  const float m1 = mlb[256 + row], l1 = mlb[384 + row];
  const int three = (t >= 22);
  float m2 = -1e30f, l2 = 0.f;
  if (three) { m2 = mlb[512 + row]; l2 = mlb[640 + row]; }

  const float m  = fmaxf(fmaxf(m0, m1), m2);
  const float w0 = __builtin_amdgcn_exp2f(m0 - m);
  const float w1 = __builtin_amdgcn_exp2f(m1 - m);

  float* op = O + (((size_t)(b * NS + (t << 7) + row)) << 7) + 4 * d4;
  fx4 a0 = *(const fx4*)op;

  const int p1 = (t <= 21) ? (t - 11) : (11 + 2 * (t - 22));
  const unsigned short* pp1 =
      Pa + (((size_t)((b * 32 + p1) * 128 + row)) << 7) + 4 * d4;
  bfv4 a1b = __builtin_bit_cast(bfv4, *(const u16x4*)pp1);
  fx4 a1;
#pragma unroll
  for (int j = 0; j < 4; ++j) a1[j] = (float)a1b[j];

  fx4 num   = a0 * w0 + a1 * w1;
  float den = w0 * l0 + w1 * l1;
  if (three) {
    const float w2 = __builtin_amdgcn_exp2f(m2 - m);
    const unsigned short* pp2 =
        Pa + (((size_t)((b * 32 + p1 + 1) * 128 + row)) << 7) + 4 * d4;
    bfv4 a2b = __builtin_bit_cast(bfv4, *(const u16x4*)pp2);
    fx4 a2;
#pragma unroll
    for (int j = 0; j < 4; ++j) a2[j] = (float)a2b[j];
    num += a2 * w2;
    den += w2 * l2;
  }
  *(fx4*)op = num * (1.0f / den);
}

extern "C" void kernel_launch(void* const* d_in, const int* in_sizes, int n_in,
                              void* d_out, int out_size, void* d_ws, size_t ws_size,
                              hipStream_t stream) {
  (void)in_sizes; (void)n_in; (void)out_size;
  const float* Q = (const float*)d_in[0];
  const float* K = (const float*)d_in[1];
  const float* V = (const float*)d_in[2];
  float* O = (float*)d_out;

  unsigned short* Kf = (unsigned short*)d_ws;               // 16 MB @ 0
  unsigned short* Vf = Kf + (size_t)NB * NS * DH;           // 16 MB @ 16M
  unsigned short* Pa = (unsigned short*)((char*)d_ws + 33554432);  // 16 MB @ 32M
  float*          Ml = (float*)((char*)d_ws + 50331648);    // 2 MB @ 48M

  const size_t NEED = 52428800;  // 50 MB
  const int split = (ws_size >= NEED) ? 1 : 0;

  prepack_kernel<<<dim3(NB * 64), dim3(256), 0, stream>>>(K, V, Kf, Vf);
  attn_kernel<<<dim3(split ? 768 : 512), dim3(256), 0, stream>>>(
      Q, Kf, Vf, O, Pa, Ml, split);
  if (split) merge_kernel<<<dim3(5376), dim3(256), 0, stream>>>(O, Pa, Ml);
}

// Round 13
// 124.510 us; speedup vs baseline: 1.0043x; 1.0043x over previous
//
#include <hip/hip_runtime.h>
#include <stdint.h>

// ScaledDotProductAttention: B=16, Nq=Nk=4096, d=128, fp32 in/out, causal.
// Flash forward, bf16 MFMA 16x16x32, swapped-QK^T (lane-local softmax).
// Round-12: 8-wave blocks (512 thr), 16 q-rows/wave -> 4 waves/SIMD (2 blk/CU)
// so MFMA dep-chains + LDS latency hide across blocks; acc halves to 32 regs
// (launch_bounds (512,4), cap 128, ~90 live -> no spill). Linear Vf layout:
// one 32-kv unit = contiguous 8KB for K and V -> STAGE = base + jb*8192,
// 2 global_load_lds per wave, near-zero address VALU. Equal 66-unit blocks:
// piece0 = big tile units [0,66) raw f32 -> O; piece1 = big rest + small tile
// (direct). 2-way merge (r6-verified form). KVBLK=32, dbuf 2x16KB LDS.
// ws: Kfrag 16MB | Vfrag 16MB | Pa 8MB @32M | Ml 512KB @40M (NEED 42.5MB).

#define NB 16
#define NS 4096
#define DH 128

typedef float          fx4   __attribute__((ext_vector_type(4)));
typedef uint32_t       ux4   __attribute__((ext_vector_type(4)));
typedef __bf16         bfv8  __attribute__((ext_vector_type(8)));
typedef __bf16         bfv4  __attribute__((ext_vector_type(4)));
typedef unsigned short u16x4 __attribute__((ext_vector_type(4)));

typedef const uint32_t __attribute__((address_space(1))) glob_u32;
typedef uint32_t       __attribute__((address_space(3))) lds_u32;

__device__ __forceinline__ fx4 mfma16(bfv8 a, bfv8 b, fx4 c) {
  return __builtin_amdgcn_mfma_f32_16x16x32_bf16(a, b, c, 0, 0, 0);
}

// ---------------- fused prepass: K,V fp32 -> fragment-packed bf16 ----------------
// One block per (batch, kv-block-of-64). lane = g*16+ln16.
//  Kfrag[b][kv64][tt(4)][c(4)][lane][8]: K[b][kvb+16tt+ln16][32c+8g+e]
//    -> 32-kv unit u = kv64*2 + (tt>>1) is contiguous 8KB.
//  Vfrag (NEW linear): [b][kv64][c(2)][dt(8)][lane][8]: V^T row d=16dt+ln16,
//    unit u = kv64*2 + c contiguous 8KB; within unit elem map (local kv):
//    e<4 -> 4g+e ; e>=4 -> 16+4g+(e-4)   (same map r4-r11 verified).
__global__ void __launch_bounds__(256) prepack_kernel(
    const float* __restrict__ K, const float* __restrict__ V,
    unsigned short* __restrict__ Kf, unsigned short* __restrict__ Vf) {
  __shared__ __align__(16) unsigned short tile[64][136];
  const int bid = blockIdx.x;
  const int b = bid >> 6, kvblk = bid & 63;
  const int kvb = kvblk << 6;
  const int tid = threadIdx.x;
  const size_t fbase = ((size_t)(b * 64 + kvblk)) * 8192;  // u16 units

  {
    const int tt = tid >> 6, lane = tid & 63;
    const int ln16 = lane & 15, g = lane >> 4;
    const float* kp = K + (((size_t)(b * NS + kvb + 16 * tt + ln16)) << 7) + 8 * g;
    unsigned short* op = Kf + fbase + tt * 2048 + lane * 8;
#pragma unroll
    for (int c = 0; c < 4; ++c) {
      fx4 a0 = *(const fx4*)(kp + 32 * c);
      fx4 a1 = *(const fx4*)(kp + 32 * c + 4);
      bfv8 t;
#pragma unroll
      for (int j = 0; j < 4; ++j) {
        t[j]     = (__bf16)a0[j];
        t[j + 4] = (__bf16)a1[j];
      }
      *(ux4*)(op + c * 512) = __builtin_bit_cast(ux4, t);
    }
  }

  {
    const int r = tid >> 2, cq = tid & 3;
    const float* vp = V + (((size_t)(b * NS + kvb + r)) << 7) + 32 * cq;
#pragma unroll
    for (int h = 0; h < 4; ++h) {
      fx4 f0 = *(const fx4*)(vp + 8 * h);
      fx4 f1 = *(const fx4*)(vp + 8 * h + 4);
      bfv8 t;
#pragma unroll
      for (int j = 0; j < 4; ++j) {
        t[j]     = (__bf16)f0[j];
        t[j + 4] = (__bf16)f1[j];
      }
      *(ux4*)&tile[r][32 * cq + 8 * h] = __builtin_bit_cast(ux4, t);
    }
  }
  __syncthreads();
  {
    const int dt = tid >> 5, c = (tid >> 4) & 1, ln16 = tid & 15;
    const int d = 16 * dt + ln16;
    // linear layout: c*4096 + dt*512 (u16), lane*8 within
    unsigned short* op = Vf + fbase + c * 4096 + dt * 512 + ln16 * 8;
#pragma unroll
    for (int g = 0; g < 4; ++g) {
      unsigned short e[8];
#pragma unroll
      for (int j = 0; j < 4; ++j) {
        e[j]     = tile[32 * c + 4 * g + j][d];
        e[j + 4] = tile[32 * c + 16 + 4 * g + j][d];
      }
      *(ux4*)(op + g * 128) = *(const ux4*)e;  // lane*8 = (g*16+ln16)*8
    }
  }
}

// ---------------- main: causal flash attention, 8-wave blocks ----------------
// Units = 32-kv. Tile t needs 4t+4 units. Group v: big T=31-v (128-4v units)
// + small v (4v+4) = 132; two blocks of 66:
//   piece0: T units [0,66), mode 1 (raw f32 -> O), Ml slot0
//   piece1: T units [66,128-4v), mode 2 (bf16 -> Pa), Ml slot1; then tile v
//           full, mode 0 (direct normalized write)
__global__ void __launch_bounds__(512, 4) attn_kernel(
    const float* __restrict__ Q, const unsigned short* __restrict__ Kf,
    const unsigned short* __restrict__ Vf, float* __restrict__ O,
    unsigned short* __restrict__ Pa, float* __restrict__ Ml, int split) {
  __shared__ __align__(16) unsigned char sm[32768];  // 2 x (K 8K | V 8K)

  const int wid  = blockIdx.x;
  const int tid  = threadIdx.x;
  const int w    = tid >> 6;        // 0..7
  const int lane = tid & 63;
  const int g    = lane >> 4;
  const int ln16 = lane & 15;

  int b, t, u0, un, mode;
  int t1 = 0, u1b = 0;
  int again = 0;

  if (split) {
    const int piece = wid >> 8;       // 0 or 1
    const int v     = (wid >> 4) & 15;
    b = wid & 15;                     // wid%8 = b%8 -> XCD pin
    t = 31 - v;                       // big tile
    if (piece == 0) {
      u0 = 0; un = 66; mode = 1;
    } else {
      u0 = 66; un = 128 - 4 * v; mode = 2;
      t1 = v; u1b = 4 * v + 4; again = 1;
    }
  } else {  // fallback: full tiles, paired big/small, direct write
    const int half = wid >> 8, ii = wid & 255;
    b = ii & 15;
    const int qi = ii >> 4;
    t = half ? qi : 31 - qi;
    u0 = 0; un = 4 * t + 4; mode = 0;
  }

  const float SCALE = 0.12753102f;  // log2(e)/sqrt(128): exp2-domain scores
  const fx4 z4 = {0.f, 0.f, 0.f, 0.f};

  const unsigned char* kfB = (const unsigned char*)Kf + (size_t)b * 1048576;
  const unsigned char* vfB = (const unsigned char*)Vf + (size_t)b * 1048576;

  // stage 32-kv unit jb into LDS buffer at byte offset bo. Both K and V are
  // contiguous 8KB at jb*8192. Wave w moves K chunk w and V chunk w (1KB ea).
#define STAGE(jb, bo)                                                         \
  do {                                                                        \
    const unsigned char* gk = kfB + (size_t)(jb) * 8192;                      \
    const unsigned char* gv = vfB + (size_t)(jb) * 8192;                      \
    __builtin_amdgcn_global_load_lds((glob_u32*)(gk + w * 1024 + lane * 16),  \
                                     (lds_u32*)(sm + (bo) + w * 1024), 16, 0, 0); \
    __builtin_amdgcn_global_load_lds((glob_u32*)(gv + w * 1024 + lane * 16),  \
                                     (lds_u32*)(sm + (bo) + 8192 + w * 1024), 16, 0, 0); \
  } while (0)

  for (;;) {  // 1 or 2 pieces
    const int qw = (t << 7) + 16 * w;   // wave's 16 q-rows base

    // Q fragments, pre-scaled (16 VGPR)
    bfv8 qf[4];
#pragma unroll
    for (int c = 0; c < 4; ++c) {
      const float* qp = Q + (((size_t)(b * NS + qw + ln16)) << 7) + 32 * c + 8 * g;
      fx4 a0 = *(const fx4*)qp;
      fx4 a1 = *(const fx4*)(qp + 4);
      bfv8 tt_;
#pragma unroll
      for (int j = 0; j < 4; ++j) {
        tt_[j]     = (__bf16)(a0[j] * SCALE);
        tt_[j + 4] = (__bf16)(a1[j] * SCALE);
      }
      qf[c] = tt_;
    }

    fx4 acc[8];  // 32 regs
#pragma unroll
    for (int dt = 0; dt < 8; ++dt) acc[dt] = z4;
    float mrun = -1e30f;
    float lsum = 0.f;

    const int nkvw = (qw >> 5) + 1;  // causal limit in 32-units
    const int qrow = qw + ln16;

    STAGE(u0, 0);
    asm volatile("s_waitcnt vmcnt(0)" ::: "memory");
    __builtin_amdgcn_s_barrier();
    asm volatile("" ::: "memory");

    int cur = 0;
    for (int jb = u0; jb < un; ++jb) {
      if (jb + 1 < un) STAGE(jb + 1, (cur ^ 1) * 16384);  // hides under compute

      if (jb < nkvw) {
        const unsigned char* kb = sm + cur * 16384;
        const unsigned char* vb = kb + 8192;

        // ---- QK^T (swapped: A=K rows->kv, B=Q cols->q) ----
        fx4 s[2];
        s[0] = z4; s[1] = z4;
        __builtin_amdgcn_s_setprio(1);
#pragma unroll
        for (int tt = 0; tt < 2; ++tt) {
#pragma unroll
          for (int c = 0; c < 4; ++c) {
            bfv8 kfr = *(const bfv8*)(kb + tt * 4096 + c * 1024 + lane * 16);
            s[tt] = mfma16(kfr, qf[c], s[tt]);
          }
        }
        __builtin_amdgcn_s_setprio(0);

        // ---- causal mask (last unit of this wave only) ----
        const int kvb = jb << 5;
        if (kvb + 31 > qrow - ln16 + 0 + (qw - qw) + qw - qw + qw % 1 + 31 * 0 + (qw & 0) ? (kvb + 31 > qw) : 0) { /* never taken branch guard */ }
        if (kvb + 31 > qw) {
#pragma unroll
          for (int tt = 0; tt < 2; ++tt)
#pragma unroll
            for (int r = 0; r < 4; ++r) {
              int kvpos = kvb + 16 * tt + 4 * g + r;
              if (kvpos > qrow) s[tt][r] = -1e30f;
            }
        }

        // ---- online softmax (exp2 domain, lane-local, defer-max THR=8) ----
        fx4 m4 = __builtin_elementwise_max(s[0], s[1]);
        float pm = fmaxf(fmaxf(m4[0], m4[1]), fmaxf(m4[2], m4[3]));
        pm = fmaxf(pm, __shfl_xor(pm, 16));
        pm = fmaxf(pm, __shfl_xor(pm, 32));
        if (__any(pm > mrun + 8.0f)) {
          float mn = fmaxf(mrun, pm);
          float f  = __builtin_amdgcn_exp2f(mrun - mn);
          lsum *= f;
#pragma unroll
          for (int dt = 0; dt < 8; ++dt) acc[dt] *= f;
          mrun = mn;
        }
#pragma unroll
        for (int tt = 0; tt < 2; ++tt)
#pragma unroll
          for (int r = 0; r < 4; ++r)
            s[tt][r] = __builtin_amdgcn_exp2f(s[tt][r] - mrun);
        fx4 r4 = s[0] + s[1];
        float rs = (r4[0] + r4[1]) + (r4[2] + r4[3]);
        rs += __shfl_xor(rs, 16);
        rs += __shfl_xor(rs, 32);
        lsum += rs;
        // pack P^T: j<4 -> local kv 4g+j (tt=0), j>=4 -> 16+4g+(j-4) (tt=1)
        bfv8 pb;
#pragma unroll
        for (int j = 0; j < 4; ++j) {
          pb[j]     = (__bf16)s[0][j];
          pb[j + 4] = (__bf16)s[1][j];
        }

        // ---- PV (A = V^T rows->d, B = P^T col->q); V read inline ----
        __builtin_amdgcn_s_setprio(1);
#pragma unroll
        for (int dt = 0; dt < 8; ++dt) {
          bfv8 vfr = *(const bfv8*)(vb + dt * 1024 + lane * 16);
          acc[dt] = mfma16(vfr, pb, acc[dt]);
        }
        __builtin_amdgcn_s_setprio(0);
      }

      asm volatile("s_waitcnt vmcnt(0)" ::: "memory");  // next tile staged
      __builtin_amdgcn_s_barrier();
      asm volatile("" ::: "memory");
      cur ^= 1;
    }

    // ---- epilogue per mode ----
    if (mode == 0) {  // final: O = acc/l
      float inv = 1.0f / lsum;
      float* ob = O + (((size_t)(b * NS + qrow)) << 7) + 4 * g;
#pragma unroll
      for (int dt = 0; dt < 8; ++dt) *(fx4*)(ob + 16 * dt) = acc[dt] * inv;
    } else {
      if (mode == 1) {  // piece0: raw f32 acc -> O (merged later)
        float* ob = O + (((size_t)(b * NS + qrow)) << 7) + 4 * g;
#pragma unroll
        for (int dt = 0; dt < 8; ++dt) *(fx4*)(ob + 16 * dt) = acc[dt];
      } else {  // piece1 big-part: bf16 acc -> Pa[b][t-16]
        const int row = 16 * w + ln16;
        unsigned short* pp =
            Pa + (((size_t)((b * 16 + (t - 16)) * 128 + row)) << 7) + 4 * g;
#pragma unroll
        for (int dt = 0; dt < 8; ++dt) {
          bfv4 t4;
#pragma unroll
          for (int j = 0; j < 4; ++j) t4[j] = (__bf16)acc[dt][j];
          *(u16x4*)(pp + 16 * dt) = __builtin_bit_cast(u16x4, t4);
        }
      }
      if (g == 0) {  // (m,l) -> Ml[b][t-16][slot][2][128]
        const int slot = mode - 1;
        const int row = 16 * w + ln16;
        float* mlp = Ml + (size_t)(((b * 16 + (t - 16)) * 2 + slot) * 2) * 128;
        mlp[row]       = mrun;
        mlp[128 + row] = lsum;
      }
    }

    if (!again) break;
    again = 0;
    t = t1; u0 = 0; un = u1b; mode = 0;
  }
#undef STAGE
}

// ---------------- merge: combine piece0 (raw f32 in O) with piece1 (bf16 Pa) ----------------
// (r6-verified structure) tiles t=16..31.
__global__ void __launch_bounds__(256) merge_kernel(
    float* __restrict__ O, const unsigned short* __restrict__ Pa,
    const float* __restrict__ Ml) {
  const int gid = blockIdx.x * 256 + threadIdx.x;  // 1,048,576 threads exact
  const int d4  = gid & 31;
  const int rg  = gid >> 5;       // 0..32767
  const int b   = rg >> 11;
  const int r2  = rg & 2047;
  const int tt  = r2 >> 7;        // tile t = 16+tt
  const int row = r2 & 127;

  const float* mlp = Ml + (size_t)((b * 16 + tt) * 4) * 128;
  const float m1 = mlp[row],       l1 = mlp[128 + row];
  const float m2 = mlp[256 + row], l2 = mlp[384 + row];
  const float m  = fmaxf(m1, m2);
  const float w1 = __builtin_amdgcn_exp2f(m1 - m);
  const float w2 = __builtin_amdgcn_exp2f(m2 - m);

  float* op = O + (((size_t)(b * NS + (16 + tt) * 128 + row)) << 7) + 4 * d4;
  fx4 a1 = *(const fx4*)op;
  const unsigned short* pp =
      Pa + (((size_t)((b * 16 + tt) * 128 + row)) << 7) + 4 * d4;
  bfv4 a2b = __builtin_bit_cast(bfv4, *(const u16x4*)pp);
  fx4 a2;
#pragma unroll
  for (int j = 0; j < 4; ++j) a2[j] = (float)a2b[j];

  const float inv = 1.0f / (w1 * l1 + w2 * l2);
  fx4 o = (a1 * w1 + a2 * w2) * inv;
  *(fx4*)op = o;
}

extern "C" void kernel_launch(void* const* d_in, const int* in_sizes, int n_in,
                              void* d_out, int out_size, void* d_ws, size_t ws_size,
                              hipStream_t stream) {
  (void)in_sizes; (void)n_in; (void)out_size;
  const float* Q = (const float*)d_in[0];
  const float* K = (const float*)d_in[1];
  const float* V = (const float*)d_in[2];
  float* O = (float*)d_out;

  unsigned short* Kf = (unsigned short*)d_ws;                      // 16 MB @ 0
  unsigned short* Vf = Kf + (size_t)NB * NS * DH;                  // 16 MB @ 16M
  unsigned short* Pa = (unsigned short*)((char*)d_ws + 33554432);  // 8 MB  @ 32M
  float*          Ml = (float*)((char*)d_ws + 41943040);           // 512KB @ 40M

  const size_t NEED = 41943040 + 524288;  // 42,467,328 B (proven available r6)
  const int split = (ws_size >= NEED) ? 1 : 0;

  prepack_kernel<<<dim3(NB * 64), dim3(256), 0, stream>>>(K, V, Kf, Vf);
  attn_kernel<<<dim3(512), dim3(512), 0, stream>>>(Q, Kf, Vf, O, Pa, Ml, split);
  if (split) merge_kernel<<<dim3(4096), dim3(256), 0, stream>>>(O, Pa, Ml);
}